// Round 10
// baseline (991.533 us; speedup 1.0000x reference)
//
#include <hip/hip_runtime.h>
#include <math.h>

#define SS 128
#define BB 32
#define CC 16
#define DW 256
#define DC 64
#define HC 128
#define KX 384   // DW + HC
#define TT 17

typedef __attribute__((ext_vector_type(8))) short bf16x8;
typedef __attribute__((ext_vector_type(4))) float f32x4;
typedef unsigned long long ull_t;

__device__ __forceinline__ float sigf(float x) { return 1.0f / (1.0f + __expf(-x)); }
__device__ __forceinline__ float tanhfast(float x) {
  float xc = fminf(fmaxf(x, -15.f), 15.f);
  float e = __expf(2.f * xc);
  return (e - 1.f) / (e + 1.f);
}
__device__ __forceinline__ unsigned short f2bf(float x) {
  unsigned int u = __float_as_uint(x);
  u += 0x7FFF + ((u >> 16) & 1);
  return (unsigned short)(u >> 16);
}
// Relaxed agent-scope atomics ONLY (native 32/64-bit, cache-bypassing; no fences).
__device__ __forceinline__ unsigned ld_u32(const unsigned* p) {
  return __hip_atomic_load(p, __ATOMIC_RELAXED, __HIP_MEMORY_SCOPE_AGENT);
}
__device__ __forceinline__ void st_u32(unsigned* p, unsigned v) {
  __hip_atomic_store(p, v, __ATOMIC_RELAXED, __HIP_MEMORY_SCOPE_AGENT);
}
__device__ __forceinline__ ull_t ld_ull(const ull_t* p) {
  return __hip_atomic_load(p, __ATOMIC_RELAXED, __HIP_MEMORY_SCOPE_AGENT);
}
__device__ __forceinline__ void st_ull(ull_t* p, ull_t v) {
  __hip_atomic_store(p, v, __ATOMIC_RELAXED, __HIP_MEMORY_SCOPE_AGENT);
}

// ---------------------------------------------------------------- K0: char ih vocab table
__global__ __launch_bounds__(256) void k0_ihvocab(
    const float* __restrict__ Wce,
    const float* __restrict__ WihF, const float* __restrict__ bF,
    const float* __restrict__ WihB, const float* __restrict__ bB,
    float* __restrict__ ihv) {
  int blk = blockIdx.x;          // 0..199
  int d = blk / 100, v = blk % 100;
  const float* Wih = d ? WihB : WihF;
  const float* bb  = d ? bB   : bF;
  __shared__ float ce[DC];
  if (threadIdx.x < DC) ce[threadIdx.x] = Wce[v * DC + threadIdx.x];
  __syncthreads();
  int g = threadIdx.x;
  float acc = bb[g];
  #pragma unroll 16
  for (int k = 0; k < DC; ++k) acc += ce[k] * Wih[g * DC + k];
  ihv[(d * 100 + v) * 256 + g] = acc;
}

// ---------------------------------------------------------------- K1: char BiLSTM (per-chain, no global sync)
__global__ __launch_bounds__(256) void k1_char(
    const int* __restrict__ charidx,   // (B,S,C)
    const float* __restrict__ WhhF, const float* __restrict__ WhhB,
    const float* __restrict__ ihv,     // (2,100,256)
    float* __restrict__ x)             // (4096, 384)
{
  int blk = blockIdx.x;
  int d = blk >> 8;
  int n0 = (blk & 255) * 16;
  const float* Whh = d ? WhhB : WhhF;

  __shared__ float Wl[256 * 64];
  __shared__ float hl[16 * 68];

  for (int i = threadIdx.x; i < 256 * 64; i += 256) {
    int g = i >> 6, k = i & 63;
    Wl[g * 64 + (((k >> 2) ^ (g & 15)) << 2) + (k & 3)] = Whh[i];
  }
  __syncthreads();

  int hh = threadIdx.x & 63;
  int ng = threadIdx.x >> 6;
  float c[4] = {0.f, 0.f, 0.f, 0.f};
  float h[4] = {0.f, 0.f, 0.f, 0.f};
  int bb_[4], ss_[4];
  #pragma unroll
  for (int m = 0; m < 4; ++m) {
    int n = n0 + ng + 4 * m;
    bb_[m] = n >> 7; ss_[m] = n & 127;
  }

  for (int t = 0; t < CC; ++t) {
    int cpos = d ? (CC - 1 - t) : t;
    float acc[4][4];
    #pragma unroll
    for (int m = 0; m < 4; ++m) {
      int v = charidx[bb_[m] * (SS * CC) + ss_[m] * CC + cpos];
      const float* base = ihv + (d * 100 + v) * 256 + hh;
      acc[m][0] = base[0]; acc[m][1] = base[64]; acc[m][2] = base[128]; acc[m][3] = base[192];
    }
    if (t > 0) {
      #pragma unroll 4
      for (int k = 0; k < 64; k += 4) {
        int kc = k >> 2;
        float4 w4[4];
        #pragma unroll
        for (int q = 0; q < 4; ++q)
          w4[q] = *(const float4*)&Wl[(q * 64 + hh) * 64 + ((kc ^ (hh & 15)) << 2)];
        #pragma unroll
        for (int m = 0; m < 4; ++m) {
          float4 h4 = *(const float4*)&hl[(ng + 4 * m) * 68 + k];
          #pragma unroll
          for (int q = 0; q < 4; ++q)
            acc[m][q] += h4.x * w4[q].x + h4.y * w4[q].y + h4.z * w4[q].z + h4.w * w4[q].w;
        }
      }
      __syncthreads();
    }
    #pragma unroll
    for (int m = 0; m < 4; ++m) {
      float ig = sigf(acc[m][0]);
      float fg = sigf(acc[m][1]);
      float gg = tanhfast(acc[m][2]);
      float og = sigf(acc[m][3]);
      c[m] = fg * c[m] + ig * gg;
      h[m] = og * tanhfast(c[m]);
      hl[(ng + 4 * m) * 68 + hh] = h[m];
    }
    __syncthreads();
  }
  #pragma unroll
  for (int m = 0; m < 4; ++m) {
    int row = ss_[m] * BB + bb_[m];
    x[row * KX + d * 64 + hh] = h[m];
  }
}

// ---------------------------------------------------------------- K2: word embedding gather
__global__ __launch_bounds__(64) void k2_we(
    const int* __restrict__ sentence, const float* __restrict__ Wwe,
    float* __restrict__ x) {
  int row = blockIdx.x;
  int idx = sentence[row];
  const float4* src = (const float4*)(Wwe + (size_t)idx * DW);
  float4* dst = (float4*)(x + (size_t)row * KX + HC);
  dst[threadIdx.x] = src[threadIdx.x];
}

// ---------------------------------------------------------------- KCV: convert x and Wih to bf16 (packed row-major)
__global__ __launch_bounds__(256) void kcv(
    const float* __restrict__ x,
    const float* __restrict__ WihF, const float* __restrict__ WihB,
    unsigned short* __restrict__ xb, unsigned short* __restrict__ wb) {
  int i = blockIdx.x * 256 + threadIdx.x;
  const float* src; unsigned short* dst; int off;
  if (i < 196608)      { src = x;    dst = xb;              off = i; }
  else if (i < 245760) { src = WihF; dst = wb;              off = i - 196608; }
  else                 { src = WihB; dst = wb + 1024 * 384; off = i - 245760; }
  float4 a = *(const float4*)(src + (size_t)off * 8);
  float4 b = *(const float4*)(src + (size_t)off * 8 + 4);
  bf16x8 o;
  o[0] = (short)f2bf(a.x); o[1] = (short)f2bf(a.y);
  o[2] = (short)f2bf(a.z); o[3] = (short)f2bf(a.w);
  o[4] = (short)f2bf(b.x); o[5] = (short)f2bf(b.y);
  o[6] = (short)f2bf(b.z); o[7] = (short)f2bf(b.w);
  *(bf16x8*)(dst + (size_t)off * 8) = o;
}

// ---------------------------------------------------------------- K3M: word ih GEMM, bf16 MFMA
__global__ __launch_bounds__(256) void k3m(
    const unsigned short* __restrict__ xb, const unsigned short* __restrict__ wb,
    const float* __restrict__ bF, const float* __restrict__ bB,
    float* __restrict__ wg) {
  const int n0 = blockIdx.x * 128;
  const int m0 = blockIdx.y * 128;
  const int d  = n0 >> 10;
  const int gb0 = n0 & 1023;
  const float* bias = d ? bB : bF;

  __shared__ unsigned short Ab[128 * 40];
  __shared__ unsigned short Bb[128 * 40];

  const int tid = threadIdx.x;
  const int l = tid & 63, w = tid >> 6;
  const int wm = w >> 1, wn = w & 1;
  const int l15 = l & 15, q4 = l >> 4;
  const int sr = tid >> 1, shf = tid & 1;   // staging row / 32B-half

  f32x4 acc[4][4];
  #pragma unroll
  for (int mr = 0; mr < 4; ++mr)
    #pragma unroll
    for (int nr = 0; nr < 4; ++nr)
      acc[mr][nr] = (f32x4){0.f, 0.f, 0.f, 0.f};

  for (int kt = 0; kt < 12; ++kt) {
    __syncthreads();
    {
      const bf16x8* sA = (const bf16x8*)(xb + (size_t)(m0 + sr) * KX + kt * 32 + shf * 16);
      const bf16x8* sB = (const bf16x8*)(wb + (size_t)(n0 + sr) * KX + kt * 32 + shf * 16);
      bf16x8 a0 = sA[0], a1 = sA[1];
      bf16x8 b0 = sB[0], b1 = sB[1];
      *(bf16x8*)&Ab[sr * 40 + shf * 16]     = a0;
      *(bf16x8*)&Ab[sr * 40 + shf * 16 + 8] = a1;
      *(bf16x8*)&Bb[sr * 40 + shf * 16]     = b0;
      *(bf16x8*)&Bb[sr * 40 + shf * 16 + 8] = b1;
    }
    __syncthreads();
    bf16x8 Afr[4], Bfr[4];
    #pragma unroll
    for (int mr = 0; mr < 4; ++mr)
      Afr[mr] = *(const bf16x8*)&Ab[(wm * 64 + mr * 16 + l15) * 40 + q4 * 8];
    #pragma unroll
    for (int nr = 0; nr < 4; ++nr)
      Bfr[nr] = *(const bf16x8*)&Bb[(wn * 64 + nr * 16 + l15) * 40 + q4 * 8];
    #pragma unroll
    for (int mr = 0; mr < 4; ++mr)
      #pragma unroll
      for (int nr = 0; nr < 4; ++nr)
        acc[mr][nr] = __builtin_amdgcn_mfma_f32_16x16x32_bf16(Afr[mr], Bfr[nr], acc[mr][nr], 0, 0, 0);
  }

  // C/D layout: col = lane&15, row = (lane>>4)*4 + reg  [guide m89]
  #pragma unroll
  for (int nr = 0; nr < 4; ++nr) {
    int gcol = gb0 + wn * 64 + nr * 16 + l15;
    float bv = bias[gcol];
    #pragma unroll
    for (int mr = 0; mr < 4; ++mr) {
      int mrow = m0 + wm * 64 + mr * 16 + q4 * 4;
      float* dst = wg + ((size_t)(d * 4096 + mrow)) * 1024 + gcol;
      #pragma unroll
      for (int r = 0; r < 4; ++r)
        dst[(size_t)r * 1024] = acc[mr][nr][r] + bv;
    }
  }
}

// ---------------------------------------------------------------- K4: word BiLSTM recurrence (global-flag design)
// 32 WGs x 64 threads (1 wave each), 16 waves per direction. Wave widx owns
// h-cols j0w..j0w+15 (x4 gate blocks). Whh in 128 VGPRs as bf16 B-frags.
// ROUND-10 REORDER: gate prefetch for t+1 moved AFTER the flag store.
// vmem retires in issue order, so the old order (gates -> publish ->
// vmcnt(0)) serialized the 32 L3/HBM gate loads (~900cy) into the publish
// drain. Now the drain covers ONLY the 2 publish stores (~1 L3-store RT);
// the gate loads land during the next step's poll+Af window (~2 RTs).
__global__ __launch_bounds__(64, 1) void k4_word(
    const float* __restrict__ WhhF, const float* __restrict__ WhhB,
    const float* __restrict__ wg,           // (2,4096,1024) f32
    float* __restrict__ outh,               // (4096,512) f32
    unsigned short* __restrict__ hbuf,      // (2 dir, 2 parity, 32 b, 256 k) bf16
    unsigned int* __restrict__ flags) {     // per dir: 16 tags at dir*16
  const int blk = blockIdx.x;               // 0..31
  const int d = blk >> 4, widx = blk & 15;
  const int l = threadIdx.x;                // 0..63
  const int l15 = l & 15, q4 = l >> 4;
  const int j0w = widx * 16;
  const float* __restrict__ Whh = d ? WhhB : WhhF;
  unsigned short* hb_d = hbuf + d * 16384;  // 2 parities * 8192
  unsigned int* fl = flags + d * 16;

  __shared__ unsigned short hl[32 * 24];    // per-wave transpose tile, row stride 48B

  // ---- Whh B-fragments resident: lane holds B[k=ks*32+q4*8+j][n=l15]
  bf16x8 Bf[4][8];
  #pragma unroll
  for (int q = 0; q < 4; ++q) {
    const float* wr = Whh + (size_t)(q * 256 + j0w + l15) * 256 + q4 * 8;
    #pragma unroll
    for (int ks = 0; ks < 8; ++ks) {
      float4 lo = *(const float4*)(wr + ks * 32);
      float4 hi = *(const float4*)(wr + ks * 32 + 4);
      bf16x8 f;
      f[0] = (short)f2bf(lo.x); f[1] = (short)f2bf(lo.y);
      f[2] = (short)f2bf(lo.z); f[3] = (short)f2bf(lo.w);
      f[4] = (short)f2bf(hi.x); f[5] = (short)f2bf(hi.y);
      f[6] = (short)f2bf(hi.z); f[7] = (short)f2bf(hi.w);
      Bf[q][ks] = f;
    }
  }

  float cst[8];
  #pragma unroll
  for (int i = 0; i < 8; ++i) cst[i] = 0.f;

  const int rb = l >> 1;          // transpose-read row (batch) 0..31
  const int rh = l & 1;           // transpose-read half-chunk

  // ---- prologue: gates for t=0
  f32x4 acc[4][2];
  {
    const int s0 = d ? (SS - 1) : 0;
    const float* wgs = wg + ((size_t)d * 4096 + (size_t)s0 * 32) * 1024 + j0w + l15;
    #pragma unroll
    for (int q = 0; q < 4; ++q)
      #pragma unroll
      for (int mt = 0; mt < 2; ++mt)
        #pragma unroll
        for (int r = 0; r < 4; ++r)
          acc[q][mt][r] = wgs[(size_t)(q4 * 4 + r + mt * 16) * 1024 + q * 256];
  }

  for (int t = 0; t < SS; ++t) {
    const int s = d ? (SS - 1 - t) : t;

    if (t > 0) {
      // ---- wait for all 16 producer waves of this direction (relaxed polls)
      for (;;) {
        unsigned tg = ld_u32(fl + l15);
        if (__all((int)(tg >= (unsigned)t))) break;
        __builtin_amdgcn_s_sleep(1);
      }

      // ---- A-fragments of h_{t-1}: cache-bypassing 8B loads
      const unsigned short* hp = hb_d + ((t - 1) & 1) * 8192 + q4 * 8;
      bf16x8 Af[2][8];
      #pragma unroll
      for (int mt = 0; mt < 2; ++mt)
        #pragma unroll
        for (int ks = 0; ks < 8; ++ks) {
          const ull_t* p = (const ull_t*)(hp + (size_t)(l15 + mt * 16) * 256 + ks * 32);
          union { ull_t u[2]; bf16x8 v; } cvt;
          cvt.u[0] = ld_ull(p);
          cvt.u[1] = ld_ull(p + 1);
          Af[mt][ks] = cvt.v;
        }
      #pragma unroll
      for (int q = 0; q < 4; ++q)
        #pragma unroll
        for (int mt = 0; mt < 2; ++mt) {
          f32x4 c = acc[q][mt];
          #pragma unroll
          for (int ks = 0; ks < 8; ++ks)
            c = __builtin_amdgcn_mfma_f32_16x16x32_bf16(Af[mt][ks], Bf[q][ks], c, 0, 0, 0);
          acc[q][mt] = c;
        }
    }

    // ---- activations; lane owns (b = q4*4+r+mt*16, col = j0w+l15)
    float hv[8];
    #pragma unroll
    for (int mt = 0; mt < 2; ++mt)
      #pragma unroll
      for (int r = 0; r < 4; ++r) {
        int ix = mt * 4 + r;
        float ig = sigf(acc[0][mt][r]);
        float fg = sigf(acc[1][mt][r]);
        float gg = tanhfast(acc[2][mt][r]);
        float og = sigf(acc[3][mt][r]);
        float c2 = fg * cst[ix] + ig * gg;
        cst[ix] = c2;
        hv[ix] = og * tanhfast(c2);
      }

    // ---- wave-local LDS transpose: [b][col] tile, then 8B-aligned publish
    #pragma unroll
    for (int mt = 0; mt < 2; ++mt)
      #pragma unroll
      for (int r = 0; r < 4; ++r)
        hl[(q4 * 4 + r + mt * 16) * 24 + l15] = f2bf(hv[mt * 4 + r]);
    ull_t plo = *(const ull_t*)&hl[rb * 24 + rh * 8];
    ull_t phi = *(const ull_t*)&hl[rb * 24 + rh * 8 + 4];
    ull_t* dst = (ull_t*)(hb_d + (t & 1) * 8192 + (size_t)rb * 256 + j0w + rh * 8);
    st_ull(dst, plo);
    st_ull(dst + 1, phi);
    // drain ONLY this wave's publish stores (nothing older outstanding), tag
    asm volatile("s_waitcnt vmcnt(0)" ::: "memory");
    if (l == 0) st_u32(fl + widx, (unsigned)(t + 1));

    // ---- gate prefetch for t+1 (AFTER flag: off the drain path; lands
    //      during next step's poll+Af window)
    if (t < SS - 1) {
      const int sn = d ? (SS - 2 - t) : (t + 1);
      const float* wgs = wg + ((size_t)d * 4096 + (size_t)sn * 32) * 1024 + j0w + l15;
      #pragma unroll
      for (int q = 0; q < 4; ++q)
        #pragma unroll
        for (int mt = 0; mt < 2; ++mt)
          #pragma unroll
          for (int r = 0; r < 4; ++r)
            acc[q][mt][r] = wgs[(size_t)(q4 * 4 + r + mt * 16) * 1024 + q * 256];
    }

    // ---- outh (non-temporal, off critical path)
    float* op = outh + (size_t)(s * 32) * 512 + d * 256 + j0w + l15;
    #pragma unroll
    for (int mt = 0; mt < 2; ++mt)
      #pragma unroll
      for (int r = 0; r < 4; ++r)
        __builtin_nontemporal_store(hv[mt * 4 + r], op + (size_t)(q4 * 4 + r + mt * 16) * 512);
  }
}

// ---------------------------------------------------------------- K5: emit GEMM (tiny)
__global__ __launch_bounds__(64) void k5_emit(
    const float* __restrict__ outh, const float* __restrict__ eW,
    const float* __restrict__ eb, float* __restrict__ em) {
  int row = blockIdx.x;
  int t = threadIdx.x;
  if (t < TT) {
    const float4* o4 = (const float4*)(outh + (size_t)row * 512);
    const float4* w4 = (const float4*)(eW + (size_t)t * 512);
    float acc = 0.f;
    #pragma unroll 16
    for (int k = 0; k < 128; ++k) {
      float4 a = o4[k], bq = w4[k];
      acc += a.x * bq.x + a.y * bq.y + a.z * bq.z + a.w * bq.w;
    }
    em[row * TT + t] = acc + eb[t];
  }
}

// ---------------------------------------------------------------- K6: CRF NLL (32 independent batches)
__global__ __launch_bounds__(64) void k6_crf(
    const int* __restrict__ sentence, const int* __restrict__ tags,
    const float* __restrict__ em, const float* __restrict__ trans,
    const float* __restrict__ startv, const float* __restrict__ endv,
    float* __restrict__ outp) {
  int b = blockIdx.x;
  int j = threadIdx.x;
  __shared__ float ash[TT];
  __shared__ float red[TT];
  float tc[TT];
  float alpha = 0.f;
  if (j < TT) {
    #pragma unroll
    for (int i = 0; i < TT; ++i) tc[i] = trans[i * TT + j];
    alpha = startv[j] + em[(0 * BB + b) * TT + j];
  }
  for (int s = 1; s < SS; ++s) {
    if (j < TT) ash[j] = alpha;
    __syncthreads();
    int m = (sentence[s * BB + b] != 1) ? 1 : 0;
    if (j < TT) {
      float mx = -1e30f;
      #pragma unroll
      for (int i = 0; i < TT; ++i) mx = fmaxf(mx, ash[i] + tc[i]);
      float sum = 0.f;
      #pragma unroll
      for (int i = 0; i < TT; ++i) sum += __expf(ash[i] + tc[i] - mx);
      float nxt = mx + __logf(sum) + em[(s * BB + b) * TT + j];
      if (m) alpha = nxt;
    }
    __syncthreads();
  }
  if (j < TT) red[j] = alpha + endv[j];
  __syncthreads();
  if (j == 0) {
    float mx = -1e30f;
    for (int i = 0; i < TT; ++i) mx = fmaxf(mx, red[i]);
    float sum = 0.f;
    for (int i = 0; i < TT; ++i) sum += __expf(red[i] - mx);
    float den = mx + __logf(sum);
    int prev = tags[0 * BB + b];
    float num = startv[prev] + em[(0 * BB + b) * TT + prev];
    for (int s = 1; s < SS; ++s) {
      int tg = tags[s * BB + b];
      if (sentence[s * BB + b] != 1) {
        num += trans[prev * TT + tg] + em[(s * BB + b) * TT + tg];
        prev = tg;
      }
    }
    num += endv[prev];
    atomicAdd(outp, den - num);
  }
}

// ---------------------------------------------------------------- launcher
extern "C" void kernel_launch(void* const* d_in, const int* in_sizes, int n_in,
                              void* d_out, int out_size, void* d_ws, size_t ws_size,
                              hipStream_t stream) {
  (void)in_sizes; (void)n_in; (void)out_size; (void)ws_size;
  const int*   sentence = (const int*)d_in[0];
  const int*   charidx  = (const int*)d_in[1];
  const int*   tags     = (const int*)d_in[2];
  const float* Wwe   = (const float*)d_in[3];
  const float* Wce   = (const float*)d_in[4];
  const float* cWihF = (const float*)d_in[5];
  const float* cWhhF = (const float*)d_in[6];
  const float* cbF   = (const float*)d_in[7];
  const float* wWihF = (const float*)d_in[8];
  const float* wWhhF = (const float*)d_in[9];
  const float* wbF   = (const float*)d_in[10];
  const float* cWihB = (const float*)d_in[11];
  const float* cWhhB = (const float*)d_in[12];
  const float* cbB   = (const float*)d_in[13];
  const float* wWihB = (const float*)d_in[14];
  const float* wWhhB = (const float*)d_in[15];
  const float* wbB   = (const float*)d_in[16];
  const float* eW    = (const float*)d_in[17];
  const float* eb    = (const float*)d_in[18];
  const float* trans = (const float*)d_in[19];
  const float* startv= (const float*)d_in[20];
  const float* endv  = (const float*)d_in[21];

  char* ws = (char*)d_ws;
  unsigned int*   flags = (unsigned int*)(ws + 0);        //     512 B
  float*          ihv   = (float*)(ws + 512);             //  204800 B
  float*          x     = (float*)(ws + 205312);          // 6291456 B
  float*          wg    = (float*)(ws + 6496768);         // 33554432 B
  unsigned short* hbuf  = (unsigned short*)(ws + 40051200); // 65536 B
  float*          outh  = (float*)(ws + 40116736);        // 8388608 B
  float*          em    = (float*)(ws + 48505344);        //  278528 B
  // xb (3,145,728 B) + wb (1,572,864 B) alias the outh region: outh is only
  // written by k4 (after k3m has consumed xb/wb) and read by k5.
  unsigned short* xb = (unsigned short*)(ws + 40116736);
  unsigned short* wb = (unsigned short*)(ws + 40116736 + 3145728);
  // total ws usage: 48,783,872 B (unchanged)

  hipMemsetAsync(flags, 0, 512, stream);
  hipMemsetAsync(d_out, 0, sizeof(float), stream);

  k0_ihvocab<<<200, 256, 0, stream>>>(Wce, cWihF, cbF, cWihB, cbB, ihv);
  k1_char<<<512, 256, 0, stream>>>(charidx, cWhhF, cWhhB, ihv, x);
  k2_we<<<4096, 64, 0, stream>>>(sentence, Wwe, x);
  kcv<<<1152, 256, 0, stream>>>(x, wWihF, wWihB, xb, wb);
  k3m<<<dim3(16, 32), 256, 0, stream>>>(xb, wb, wbF, wbB, wg);
  k4_word<<<32, 64, 0, stream>>>(wWhhF, wWhhB, wg, outh, hbuf, flags);
  k5_emit<<<4096, 64, 0, stream>>>(outh, eW, eb, em);
  k6_crf<<<32, 64, 0, stream>>>(sentence, tags, em, trans, startv, endv, (float*)d_out);
}

// Round 12
// 967.095 us; speedup vs baseline: 1.0253x; 1.0253x over previous
//
#include <hip/hip_runtime.h>
#include <math.h>

#define SS 128
#define BB 32
#define CC 16
#define DW 256
#define DC 64
#define HC 128
#define KX 384   // DW + HC
#define TT 17

typedef __attribute__((ext_vector_type(8))) short bf16x8;
typedef __attribute__((ext_vector_type(4))) float f32x4;
typedef unsigned long long ull_t;

__device__ __forceinline__ float sigf(float x) { return 1.0f / (1.0f + __expf(-x)); }
__device__ __forceinline__ float tanhfast(float x) {
  float xc = fminf(fmaxf(x, -15.f), 15.f);
  float e = __expf(2.f * xc);
  return (e - 1.f) / (e + 1.f);
}
__device__ __forceinline__ unsigned short f2bf(float x) {
  unsigned int u = __float_as_uint(x);
  u += 0x7FFF + ((u >> 16) & 1);
  return (unsigned short)(u >> 16);
}
// Relaxed agent-scope atomics ONLY (native 32/64-bit, cache-bypassing; no fences).
__device__ __forceinline__ unsigned ld_u32(const unsigned* p) {
  return __hip_atomic_load(p, __ATOMIC_RELAXED, __HIP_MEMORY_SCOPE_AGENT);
}
__device__ __forceinline__ void st_u32(unsigned* p, unsigned v) {
  __hip_atomic_store(p, v, __ATOMIC_RELAXED, __HIP_MEMORY_SCOPE_AGENT);
}
__device__ __forceinline__ ull_t ld_ull(const ull_t* p) {
  return __hip_atomic_load(p, __ATOMIC_RELAXED, __HIP_MEMORY_SCOPE_AGENT);
}
__device__ __forceinline__ void st_ull(ull_t* p, ull_t v) {
  __hip_atomic_store(p, v, __ATOMIC_RELAXED, __HIP_MEMORY_SCOPE_AGENT);
}

// ---------------------------------------------------------------- K0: char ih vocab table
__global__ __launch_bounds__(256) void k0_ihvocab(
    const float* __restrict__ Wce,
    const float* __restrict__ WihF, const float* __restrict__ bF,
    const float* __restrict__ WihB, const float* __restrict__ bB,
    float* __restrict__ ihv) {
  int blk = blockIdx.x;          // 0..199
  int d = blk / 100, v = blk % 100;
  const float* Wih = d ? WihB : WihF;
  const float* bb  = d ? bB   : bF;
  __shared__ float ce[DC];
  if (threadIdx.x < DC) ce[threadIdx.x] = Wce[v * DC + threadIdx.x];
  __syncthreads();
  int g = threadIdx.x;
  float acc = bb[g];
  #pragma unroll 16
  for (int k = 0; k < DC; ++k) acc += ce[k] * Wih[g * DC + k];
  ihv[(d * 100 + v) * 256 + g] = acc;
}

// ---------------------------------------------------------------- K1: char BiLSTM (round-9 VALU version, passed 3x)
// Only change vs round 9: final hT write goes directly to bf16 xb
// (cols d*64..d*64+63), removing the f32 x buffer + kcv x-conversion.
__global__ __launch_bounds__(256) void k1_char(
    const int* __restrict__ charidx,   // (B,S,C)
    const float* __restrict__ WhhF, const float* __restrict__ WhhB,
    const float* __restrict__ ihv,     // (2,100,256)
    unsigned short* __restrict__ xb)   // (4096,384) bf16
{
  int blk = blockIdx.x;
  int d = blk >> 8;
  int n0 = (blk & 255) * 16;
  const float* Whh = d ? WhhB : WhhF;

  __shared__ float Wl[256 * 64];
  __shared__ float hl[16 * 68];

  for (int i = threadIdx.x; i < 256 * 64; i += 256) {
    int g = i >> 6, k = i & 63;
    Wl[g * 64 + (((k >> 2) ^ (g & 15)) << 2) + (k & 3)] = Whh[i];
  }
  __syncthreads();

  int hh = threadIdx.x & 63;
  int ng = threadIdx.x >> 6;
  float c[4] = {0.f, 0.f, 0.f, 0.f};
  float h[4] = {0.f, 0.f, 0.f, 0.f};
  int bb_[4], ss_[4];
  #pragma unroll
  for (int m = 0; m < 4; ++m) {
    int n = n0 + ng + 4 * m;
    bb_[m] = n >> 7; ss_[m] = n & 127;
  }

  for (int t = 0; t < CC; ++t) {
    int cpos = d ? (CC - 1 - t) : t;
    float acc[4][4];
    #pragma unroll
    for (int m = 0; m < 4; ++m) {
      int v = charidx[bb_[m] * (SS * CC) + ss_[m] * CC + cpos];
      const float* base = ihv + (d * 100 + v) * 256 + hh;
      acc[m][0] = base[0]; acc[m][1] = base[64]; acc[m][2] = base[128]; acc[m][3] = base[192];
    }
    if (t > 0) {
      #pragma unroll 4
      for (int k = 0; k < 64; k += 4) {
        int kc = k >> 2;
        float4 w4[4];
        #pragma unroll
        for (int q = 0; q < 4; ++q)
          w4[q] = *(const float4*)&Wl[(q * 64 + hh) * 64 + ((kc ^ (hh & 15)) << 2)];
        #pragma unroll
        for (int m = 0; m < 4; ++m) {
          float4 h4 = *(const float4*)&hl[(ng + 4 * m) * 68 + k];
          #pragma unroll
          for (int q = 0; q < 4; ++q)
            acc[m][q] += h4.x * w4[q].x + h4.y * w4[q].y + h4.z * w4[q].z + h4.w * w4[q].w;
        }
      }
      __syncthreads();
    }
    #pragma unroll
    for (int m = 0; m < 4; ++m) {
      float ig = sigf(acc[m][0]);
      float fg = sigf(acc[m][1]);
      float gg = tanhfast(acc[m][2]);
      float og = sigf(acc[m][3]);
      c[m] = fg * c[m] + ig * gg;
      h[m] = og * tanhfast(c[m]);
      hl[(ng + 4 * m) * 68 + hh] = h[m];
    }
    __syncthreads();
  }
  #pragma unroll
  for (int m = 0; m < 4; ++m) {
    int row = ss_[m] * BB + bb_[m];
    xb[(size_t)row * KX + d * 64 + hh] = f2bf(h[m]);
  }
}

// ---------------------------------------------------------------- K2: word embedding gather (bf16 direct)
__global__ __launch_bounds__(64) void k2_we(
    const int* __restrict__ sentence, const float* __restrict__ Wwe,
    unsigned short* __restrict__ xb) {
  int row = blockIdx.x;
  int idx = sentence[row];
  float4 v = ((const float4*)(Wwe + (size_t)idx * DW))[threadIdx.x];
  ull_t p = (ull_t)f2bf(v.x) | ((ull_t)f2bf(v.y) << 16) |
            ((ull_t)f2bf(v.z) << 32) | ((ull_t)f2bf(v.w) << 48);
  *(ull_t*)(xb + (size_t)row * KX + HC + threadIdx.x * 4) = p;
}

// ---------------------------------------------------------------- KCV: convert Wih weights to bf16 (packed row-major)
// wb: (2048,384) bf16 (rows 0..1023 = F, 1024..2047 = B). 98304 octets.
__global__ __launch_bounds__(256) void kcv(
    const float* __restrict__ WihF, const float* __restrict__ WihB,
    unsigned short* __restrict__ wb) {
  int i = blockIdx.x * 256 + threadIdx.x;
  const float* src; unsigned short* dst; int off;
  if (i < 49152) { src = WihF; dst = wb;              off = i; }
  else           { src = WihB; dst = wb + 1024 * 384; off = i - 49152; }
  float4 a = *(const float4*)(src + (size_t)off * 8);
  float4 b = *(const float4*)(src + (size_t)off * 8 + 4);
  bf16x8 o;
  o[0] = (short)f2bf(a.x); o[1] = (short)f2bf(a.y);
  o[2] = (short)f2bf(a.z); o[3] = (short)f2bf(a.w);
  o[4] = (short)f2bf(b.x); o[5] = (short)f2bf(b.y);
  o[6] = (short)f2bf(b.z); o[7] = (short)f2bf(b.w);
  *(bf16x8*)(dst + (size_t)off * 8) = o;
}

// ---------------------------------------------------------------- K3M: word ih GEMM, bf16 MFMA (round-9 version, passed 2x)
__global__ __launch_bounds__(256) void k3m(
    const unsigned short* __restrict__ xb, const unsigned short* __restrict__ wb,
    const float* __restrict__ bF, const float* __restrict__ bB,
    float* __restrict__ wg) {
  const int n0 = blockIdx.x * 128;
  const int m0 = blockIdx.y * 128;
  const int d  = n0 >> 10;
  const int gb0 = n0 & 1023;
  const float* bias = d ? bB : bF;

  __shared__ unsigned short Ab[128 * 40];
  __shared__ unsigned short Bb[128 * 40];

  const int tid = threadIdx.x;
  const int l = tid & 63, w = tid >> 6;
  const int wm = w >> 1, wn = w & 1;
  const int l15 = l & 15, q4 = l >> 4;
  const int sr = tid >> 1, shf = tid & 1;   // staging row / 32B-half

  f32x4 acc[4][4];
  #pragma unroll
  for (int mr = 0; mr < 4; ++mr)
    #pragma unroll
    for (int nr = 0; nr < 4; ++nr)
      acc[mr][nr] = (f32x4){0.f, 0.f, 0.f, 0.f};

  for (int kt = 0; kt < 12; ++kt) {
    __syncthreads();
    {
      const bf16x8* sA = (const bf16x8*)(xb + (size_t)(m0 + sr) * KX + kt * 32 + shf * 16);
      const bf16x8* sB = (const bf16x8*)(wb + (size_t)(n0 + sr) * KX + kt * 32 + shf * 16);
      bf16x8 a0 = sA[0], a1 = sA[1];
      bf16x8 b0 = sB[0], b1 = sB[1];
      *(bf16x8*)&Ab[sr * 40 + shf * 16]     = a0;
      *(bf16x8*)&Ab[sr * 40 + shf * 16 + 8] = a1;
      *(bf16x8*)&Bb[sr * 40 + shf * 16]     = b0;
      *(bf16x8*)&Bb[sr * 40 + shf * 16 + 8] = b1;
    }
    __syncthreads();
    bf16x8 Afr[4], Bfr[4];
    #pragma unroll
    for (int mr = 0; mr < 4; ++mr)
      Afr[mr] = *(const bf16x8*)&Ab[(wm * 64 + mr * 16 + l15) * 40 + q4 * 8];
    #pragma unroll
    for (int nr = 0; nr < 4; ++nr)
      Bfr[nr] = *(const bf16x8*)&Bb[(wn * 64 + nr * 16 + l15) * 40 + q4 * 8];
    #pragma unroll
    for (int mr = 0; mr < 4; ++mr)
      #pragma unroll
      for (int nr = 0; nr < 4; ++nr)
        acc[mr][nr] = __builtin_amdgcn_mfma_f32_16x16x32_bf16(Afr[mr], Bfr[nr], acc[mr][nr], 0, 0, 0);
  }

  // C/D layout: col = lane&15, row = (lane>>4)*4 + reg  [guide m89]
  #pragma unroll
  for (int nr = 0; nr < 4; ++nr) {
    int gcol = gb0 + wn * 64 + nr * 16 + l15;
    float bv = bias[gcol];
    #pragma unroll
    for (int mr = 0; mr < 4; ++mr) {
      int mrow = m0 + wm * 64 + mr * 16 + q4 * 4;
      float* dst = wg + ((size_t)(d * 4096 + mrow)) * 1024 + gcol;
      #pragma unroll
      for (int r = 0; r < 4; ++r)
        dst[(size_t)r * 1024] = acc[mr][nr][r] + bv;
    }
  }
}

// ---------------------------------------------------------------- K4: word BiLSTM recurrence (round-9 global-flag design, 520us x5)
// 32 WGs x 64 threads (1 wave each), 16 waves per direction. Gate loads at
// the TOP of each iteration (long latency cover: poll+Af window) -- round-10
// proved moving them later regresses (+48us). ~3 coherence RTs/step is this
// protocol's structural floor.
__global__ __launch_bounds__(64, 1) void k4_word(
    const float* __restrict__ WhhF, const float* __restrict__ WhhB,
    const float* __restrict__ wg,           // (2,4096,1024) f32
    float* __restrict__ outh,               // (4096,512) f32
    unsigned short* __restrict__ hbuf,      // (2 dir, 2 parity, 32 b, 256 k) bf16
    unsigned int* __restrict__ flags) {     // per dir: 16 tags at dir*16
  const int blk = blockIdx.x;               // 0..31
  const int d = blk >> 4, widx = blk & 15;
  const int l = threadIdx.x;                // 0..63
  const int l15 = l & 15, q4 = l >> 4;
  const int j0w = widx * 16;
  const float* __restrict__ Whh = d ? WhhB : WhhF;
  unsigned short* hb_d = hbuf + d * 16384;  // 2 parities * 8192
  unsigned int* fl = flags + d * 16;

  __shared__ unsigned short hl[32 * 24];    // per-wave transpose tile, row stride 48B

  // ---- Whh B-fragments resident: lane holds B[k=ks*32+q4*8+j][n=l15]
  bf16x8 Bf[4][8];
  #pragma unroll
  for (int q = 0; q < 4; ++q) {
    const float* wr = Whh + (size_t)(q * 256 + j0w + l15) * 256 + q4 * 8;
    #pragma unroll
    for (int ks = 0; ks < 8; ++ks) {
      float4 lo = *(const float4*)(wr + ks * 32);
      float4 hi = *(const float4*)(wr + ks * 32 + 4);
      bf16x8 f;
      f[0] = (short)f2bf(lo.x); f[1] = (short)f2bf(lo.y);
      f[2] = (short)f2bf(lo.z); f[3] = (short)f2bf(lo.w);
      f[4] = (short)f2bf(hi.x); f[5] = (short)f2bf(hi.y);
      f[6] = (short)f2bf(hi.z); f[7] = (short)f2bf(hi.w);
      Bf[q][ks] = f;
    }
  }

  float cst[8];
  #pragma unroll
  for (int i = 0; i < 8; ++i) cst[i] = 0.f;

  const int rb = l >> 1;          // transpose-read row (batch) 0..31
  const int rh = l & 1;           // transpose-read half-chunk

  for (int t = 0; t < SS; ++t) {
    const int s = d ? (SS - 1 - t) : t;

    // ---- ih gates into MFMA C-layout (issued before the wait; overlaps poll)
    f32x4 acc[4][2];
    const float* wgs = wg + ((size_t)d * 4096 + (size_t)s * 32) * 1024 + j0w + l15;
    #pragma unroll
    for (int q = 0; q < 4; ++q)
      #pragma unroll
      for (int mt = 0; mt < 2; ++mt)
        #pragma unroll
        for (int r = 0; r < 4; ++r)
          acc[q][mt][r] = wgs[(size_t)(q4 * 4 + r + mt * 16) * 1024 + q * 256];

    if (t > 0) {
      // ---- wait for all 16 producer waves of this direction (relaxed polls)
      for (;;) {
        unsigned tg = ld_u32(fl + l15);
        if (__all((int)(tg >= (unsigned)t))) break;
        __builtin_amdgcn_s_sleep(1);
      }

      // ---- A-fragments of h_{t-1}: cache-bypassing 8B loads
      const unsigned short* hp = hb_d + ((t - 1) & 1) * 8192 + q4 * 8;
      bf16x8 Af[2][8];
      #pragma unroll
      for (int mt = 0; mt < 2; ++mt)
        #pragma unroll
        for (int ks = 0; ks < 8; ++ks) {
          const ull_t* p = (const ull_t*)(hp + (size_t)(l15 + mt * 16) * 256 + ks * 32);
          union { ull_t u[2]; bf16x8 v; } cvt;
          cvt.u[0] = ld_ull(p);
          cvt.u[1] = ld_ull(p + 1);
          Af[mt][ks] = cvt.v;
        }
      #pragma unroll
      for (int q = 0; q < 4; ++q)
        #pragma unroll
        for (int mt = 0; mt < 2; ++mt) {
          f32x4 c = acc[q][mt];
          #pragma unroll
          for (int ks = 0; ks < 8; ++ks)
            c = __builtin_amdgcn_mfma_f32_16x16x32_bf16(Af[mt][ks], Bf[q][ks], c, 0, 0, 0);
          acc[q][mt] = c;
        }
    }

    // ---- activations; lane owns (b = q4*4+r+mt*16, col = j0w+l15)
    float hv[8];
    #pragma unroll
    for (int mt = 0; mt < 2; ++mt)
      #pragma unroll
      for (int r = 0; r < 4; ++r) {
        int ix = mt * 4 + r;
        float ig = sigf(acc[0][mt][r]);
        float fg = sigf(acc[1][mt][r]);
        float gg = tanhfast(acc[2][mt][r]);
        float og = sigf(acc[3][mt][r]);
        float c2 = fg * cst[ix] + ig * gg;
        cst[ix] = c2;
        hv[ix] = og * tanhfast(c2);
      }

    // ---- wave-local LDS transpose: [b][col] tile, then 8B-aligned publish
    #pragma unroll
    for (int mt = 0; mt < 2; ++mt)
      #pragma unroll
      for (int r = 0; r < 4; ++r)
        hl[(q4 * 4 + r + mt * 16) * 24 + l15] = f2bf(hv[mt * 4 + r]);
    ull_t plo = *(const ull_t*)&hl[rb * 24 + rh * 8];
    ull_t phi = *(const ull_t*)&hl[rb * 24 + rh * 8 + 4];
    ull_t* dst = (ull_t*)(hb_d + (t & 1) * 8192 + (size_t)rb * 256 + j0w + rh * 8);
    st_ull(dst, plo);
    st_ull(dst + 1, phi);
    // drain THIS wave's publish stores, then tag (relaxed; no fence)
    asm volatile("s_waitcnt vmcnt(0)" ::: "memory");
    if (l == 0) st_u32(fl + widx, (unsigned)(t + 1));

    // ---- outh (non-temporal, off critical path)
    float* op = outh + (size_t)(s * 32) * 512 + d * 256 + j0w + l15;
    #pragma unroll
    for (int mt = 0; mt < 2; ++mt)
      #pragma unroll
      for (int r = 0; r < 4; ++r)
        __builtin_nontemporal_store(hv[mt * 4 + r], op + (size_t)(q4 * 4 + r + mt * 16) * 512);
  }
}

// ---------------------------------------------------------------- K5: emit GEMM (LDS-staged row: outh read once, coalesced)
__global__ __launch_bounds__(64) void k5_emit(
    const float* __restrict__ outh, const float* __restrict__ eW,
    const float* __restrict__ eb, float* __restrict__ em) {
  int row = blockIdx.x;
  int tid = threadIdx.x;
  __shared__ float osh[512];
  const float4* src = (const float4*)(outh + (size_t)row * 512);
  ((float4*)osh)[tid]      = src[tid];        // floats 0..255
  ((float4*)osh)[tid + 64] = src[tid + 64];   // floats 256..511
  __syncthreads();
  if (tid < TT) {
    const float4* o4 = (const float4*)osh;    // broadcast reads (conflict-free)
    const float4* w4 = (const float4*)(eW + (size_t)tid * 512);
    float acc = 0.f;
    #pragma unroll 16
    for (int k = 0; k < 128; ++k) {
      float4 a = o4[k], bq = w4[k];
      acc += a.x * bq.x + a.y * bq.y + a.z * bq.z + a.w * bq.w;
    }
    em[row * TT + tid] = acc + eb[tid];
  }
}

// ---------------------------------------------------------------- K6: CRF NLL (32 independent batches)
// Numerator moved from a 128-step serial tail on thread 0 into the s-loop
// on lane TT (idle before): overlaps the alpha scan, removes ~4 dependent
// L2 loads x 128 steps of serial latency. Identical math.
__global__ __launch_bounds__(64) void k6_crf(
    const int* __restrict__ sentence, const int* __restrict__ tags,
    const float* __restrict__ em, const float* __restrict__ trans,
    const float* __restrict__ startv, const float* __restrict__ endv,
    float* __restrict__ outp) {
  int b = blockIdx.x;
  int j = threadIdx.x;
  __shared__ float ash[TT];
  __shared__ float red[TT];
  __shared__ float numsh;
  float tc[TT];
  float alpha = 0.f;
  float num = 0.f; int prev = 0;
  if (j < TT) {
    #pragma unroll
    for (int i = 0; i < TT; ++i) tc[i] = trans[i * TT + j];
    alpha = startv[j] + em[(0 * BB + b) * TT + j];
  } else if (j == TT) {
    prev = tags[0 * BB + b];
    num = startv[prev] + em[(0 * BB + b) * TT + prev];
  }
  for (int s = 1; s < SS; ++s) {
    if (j < TT) ash[j] = alpha;
    __syncthreads();
    int m = (sentence[s * BB + b] != 1) ? 1 : 0;
    if (j < TT) {
      float mx = -1e30f;
      #pragma unroll
      for (int i = 0; i < TT; ++i) mx = fmaxf(mx, ash[i] + tc[i]);
      float sum = 0.f;
      #pragma unroll
      for (int i = 0; i < TT; ++i) sum += __expf(ash[i] + tc[i] - mx);
      float nxt = mx + __logf(sum) + em[(s * BB + b) * TT + j];
      if (m) alpha = nxt;
    } else if (j == TT && m) {
      int tg = tags[s * BB + b];
      num += trans[prev * TT + tg] + em[(s * BB + b) * TT + tg];
      prev = tg;
    }
    __syncthreads();
  }
  if (j < TT) red[j] = alpha + endv[j];
  if (j == TT) numsh = num + endv[prev];
  __syncthreads();
  if (j == 0) {
    float mx = -1e30f;
    for (int i = 0; i < TT; ++i) mx = fmaxf(mx, red[i]);
    float sum = 0.f;
    for (int i = 0; i < TT; ++i) sum += __expf(red[i] - mx);
    float den = mx + __logf(sum);
    atomicAdd(outp, den - numsh);
  }
}

// ---------------------------------------------------------------- launcher
extern "C" void kernel_launch(void* const* d_in, const int* in_sizes, int n_in,
                              void* d_out, int out_size, void* d_ws, size_t ws_size,
                              hipStream_t stream) {
  (void)in_sizes; (void)n_in; (void)out_size; (void)ws_size;
  const int*   sentence = (const int*)d_in[0];
  const int*   charidx  = (const int*)d_in[1];
  const int*   tags     = (const int*)d_in[2];
  const float* Wwe   = (const float*)d_in[3];
  const float* Wce   = (const float*)d_in[4];
  const float* cWihF = (const float*)d_in[5];
  const float* cWhhF = (const float*)d_in[6];
  const float* cbF   = (const float*)d_in[7];
  const float* wWihF = (const float*)d_in[8];
  const float* wWhhF = (const float*)d_in[9];
  const float* wbF   = (const float*)d_in[10];
  const float* cWihB = (const float*)d_in[11];
  const float* cWhhB = (const float*)d_in[12];
  const float* cbB   = (const float*)d_in[13];
  const float* wWihB = (const float*)d_in[14];
  const float* wWhhB = (const float*)d_in[15];
  const float* wbB   = (const float*)d_in[16];
  const float* eW    = (const float*)d_in[17];
  const float* eb    = (const float*)d_in[18];
  const float* trans = (const float*)d_in[19];
  const float* startv= (const float*)d_in[20];
  const float* endv  = (const float*)d_in[21];

  char* ws = (char*)d_ws;
  unsigned int*   flags = (unsigned int*)(ws + 0);        //     512 B
  float*          ihv   = (float*)(ws + 512);             //  204800 B
  float*          wg    = (float*)(ws + 6496768);         // 33554432 B
  unsigned short* hbuf  = (unsigned short*)(ws + 40051200); // 65536 B
  float*          outh  = (float*)(ws + 40116736);        // 8388608 B
  float*          em    = (float*)(ws + 48505344);        //  278528 B
  // xb (3,145,728 B) + wb (1,572,864 B) alias the outh region: outh is only
  // written by k4 (after k3m has consumed xb/wb) and read by k5.
  unsigned short* xb = (unsigned short*)(ws + 40116736);
  unsigned short* wb = (unsigned short*)(ws + 40116736 + 3145728);
  // total ws usage: 48,783,872 B (unchanged)

  hipMemsetAsync(flags, 0, 512, stream);
  hipMemsetAsync(d_out, 0, sizeof(float), stream);

  k0_ihvocab<<<200, 256, 0, stream>>>(Wce, cWihF, cbF, cWihB, cbB, ihv);
  k1_char<<<512, 256, 0, stream>>>(charidx, cWhhF, cWhhB, ihv, xb);
  k2_we<<<4096, 64, 0, stream>>>(sentence, Wwe, xb);
  kcv<<<384, 256, 0, stream>>>(wWihF, wWihB, wb);
  k3m<<<dim3(16, 32), 256, 0, stream>>>(xb, wb, wbF, wbB, wg);
  k4_word<<<32, 64, 0, stream>>>(wWhhF, wWhhB, wg, outh, hbuf, flags);
  k5_emit<<<4096, 64, 0, stream>>>(outh, eW, eb, em);
  k6_crf<<<32, 64, 0, stream>>>(sentence, tags, em, trans, startv, endv, (float*)d_out);
}